// Round 4
// baseline (214.626 us; speedup 1.0000x reference)
//
#include <hip/hip_runtime.h>

#define NN   128
#define NB   512
#define NMAT 2560
#define L2E  1.4426950408889634f

typedef __attribute__((ext_vector_type(4))) float  f32x4;
typedef __attribute__((ext_vector_type(4))) int    i32x4;
typedef __attribute__((ext_vector_type(8))) ushort u16x8;

__device__ __forceinline__ float fexp2(float x){ float r; asm("v_exp_f32 %0, %1" : "=v"(r) : "v"(x)); return r; }
__device__ __forceinline__ float flog2(float x){ float r; asm("v_log_f32 %0, %1" : "=v"(r) : "v"(x)); return r; }
__device__ __forceinline__ float frcp (float x){ float r; asm("v_rcp_f32 %0, %1" : "=v"(r) : "v"(x)); return r; }

__device__ __forceinline__ ushort f2bf(float f){
    unsigned u = __float_as_uint(f);
    unsigned r = (u + 0x7FFFu + ((u >> 16) & 1u)) >> 16;
    return (ushort)r;
}
__device__ __forceinline__ float bf2f(ushort h){ return __uint_as_float(((unsigned)h) << 16); }

#define MFMA16(acc, a, b) \
    asm("v_mfma_f32_16x16x32_bf16 %0, %1, %2, %0" : "+v"(acc) : "v"(a), "v"(b))

// ---------------------------------------------------------------------------
// Prep kernel: permute w2*log2e into MFMA B-fragment order, split bf16 hi/lo.
// ---------------------------------------------------------------------------
__global__ __launch_bounds__(256) void prep_kernel(
    const float* __restrict__ w2, const float* __restrict__ b2,
    ushort* __restrict__ Bhi, ushort* __restrict__ Blo, float* __restrict__ b2s)
{
    int fid = blockIdx.x * 256 + threadIdx.x;    // 0..2047
    int ct = fid >> 8, ks = (fid >> 6) & 3, lane = fid & 63;
    int c  = ct * 16 + (lane & 15);
    int k0 = ks * 32 + ((lane >> 4) << 3);
    u16x8 hi, lo;
#pragma unroll
    for (int j = 0; j < 8; j++) {
        float v = w2[c * NN + k0 + j] * L2E;
        ushort h = f2bf(v);
        hi[j] = h;
        lo[j] = f2bf(v - bf2f(h));
    }
    *(u16x8*)(Bhi + (size_t)fid * 8) = hi;
    *(u16x8*)(Blo + (size_t)fid * 8) = lo;
    if (fid < NN) b2s[fid] = b2[fid] * L2E;
}

// ---------------------------------------------------------------------------
// MLP -> la via MFMA (split bf16: hi@whi + hi@wlo + lo@whi). No LDS/barriers.
// ---------------------------------------------------------------------------
__global__ __launch_bounds__(256) void mlp_mfma_kernel(
    const float* __restrict__ x,  const float* __restrict__ w1,
    const float* __restrict__ b1, const ushort* __restrict__ Bhi,
    const ushort* __restrict__ Blo, const float* __restrict__ b2s,
    float* __restrict__ la)
{
    const int t    = threadIdx.x;
    const int w    = t >> 6;
    const int lane = t & 63;
    const int blk  = blockIdx.x;
    const int b    = blk >> 1;
    const int rh   = blk & 1;

    const int r = rh * 64 + w * 16 + (lane & 15);
    const float xv = x[b * NN + r];

    i32x4 Ahi[4], Alo[4];
#pragma unroll
    for (int ks = 0; ks < 4; ks++) {
        const int l0 = ks * 32 + ((lane >> 4) << 3);
        float4 w1a = *(const float4*)(w1 + l0);
        float4 w1b = *(const float4*)(w1 + l0 + 4);
        float4 b1a = *(const float4*)(b1 + l0);
        float4 b1b = *(const float4*)(b1 + l0 + 4);
        float h[8];
        h[0] = fmaxf(fmaf(xv, w1a.x, b1a.x), 0.f);
        h[1] = fmaxf(fmaf(xv, w1a.y, b1a.y), 0.f);
        h[2] = fmaxf(fmaf(xv, w1a.z, b1a.z), 0.f);
        h[3] = fmaxf(fmaf(xv, w1a.w, b1a.w), 0.f);
        h[4] = fmaxf(fmaf(xv, w1b.x, b1b.x), 0.f);
        h[5] = fmaxf(fmaf(xv, w1b.y, b1b.y), 0.f);
        h[6] = fmaxf(fmaf(xv, w1b.z, b1b.z), 0.f);
        h[7] = fmaxf(fmaf(xv, w1b.w, b1b.w), 0.f);
#pragma unroll
        for (int p = 0; p < 4; p++) {
            ushort h0 = f2bf(h[2 * p]);
            ushort h1 = f2bf(h[2 * p + 1]);
            ushort l0e = f2bf(h[2 * p]     - bf2f(h0));
            ushort l1e = f2bf(h[2 * p + 1] - bf2f(h1));
            ((int*)&Ahi[ks])[p] = ((int)h1 << 16) | (int)h0;
            ((int*)&Alo[ks])[p] = ((int)l1e << 16) | (int)l0e;
        }
    }

    f32x4 acc[8];
#pragma unroll
    for (int ct = 0; ct < 8; ct++) acc[ct] = (f32x4){0.f, 0.f, 0.f, 0.f};

    asm volatile("s_nop 7");

#pragma unroll
    for (int ks = 0; ks < 4; ks++) {
#pragma unroll
        for (int ct = 0; ct < 8; ct++) {
            const size_t off = ((size_t)(ct * 4 + ks) * 64 + lane) * 8;
            i32x4 bh = *(const i32x4*)(Bhi + off);
            i32x4 bl = *(const i32x4*)(Blo + off);
            MFMA16(acc[ct], Ahi[ks], bh);
            MFMA16(acc[ct], Ahi[ks], bl);
            MFMA16(acc[ct], Alo[ks], bh);
        }
    }

    asm volatile("s_nop 7");
    asm volatile("s_nop 7");
    asm volatile("s_nop 3");

    const int row0 = b * NN + rh * 64 + w * 16 + (lane >> 4) * 4;
    const int col  = lane & 15;
#pragma unroll
    for (int ct = 0; ct < 8; ct++) {
        float bb = b2s[ct * 16 + col];
        float* lp = la + (size_t)row0 * NN + ct * 16 + col;
#pragma unroll
        for (int q = 0; q < 4; q++)
            lp[(size_t)q * NN] = acc[ct][q] + bb;
    }
}

// ---------------------------------------------------------------------------
// Kernel 2: Sinkhorn, potential form, base-2 log domain, DUAL LAYOUT.
// 512 threads: tr = t>>4 (0..31), tc = t&15.
//   E[4][8]: rows tr*4..+3, cols tc*8..+7  (row reductions: shfl over tc)
//   F[8][4] = E^T slice: cols tr*4..+3, rows tc*8..+7 (col reds: shfl over tc)
// One-time LDS transpose builds F (2 passes, 34KB half-buffer).
// Per iteration: only u/t 128-float broadcasts through LDS (conflict-free),
// all reductions are DPP-friendly shfl_xor(1,2,4,8). 2 barriers/iter.
// Final store from F layout: fully coalesced, transposed for free.
// ---------------------------------------------------------------------------
__global__ __launch_bounds__(512, 5) void sinkhorn_kernel(
    const float* __restrict__ la, const float* __restrict__ noise,
    float* __restrict__ out)
{
    __shared__ float buf[64][133];   // transpose staging (half matrix)
    __shared__ float tbuf[128];
    __shared__ float ubuf[128];

    const int m  = blockIdx.x;
    const int b  = m & (NB - 1);
    const int t  = threadIdx.x;
    const int tr = t >> 4, tc = t & 15;
    const int r0 = tr * 4, c0 = tc * 8;

    const float* lab = la    + (size_t)b * NN * NN;
    const float* nb  = noise + (size_t)m * NN * NN;

    float E[4][8];
#pragma unroll
    for (int i = 0; i < 4; i++) {
        const float* lr = lab + (r0 + i) * NN + c0;
        const float* nr = nb  + (r0 + i) * NN + c0;
        float4 a0 = *(const float4*)(lr);
        float4 a1 = *(const float4*)(lr + 4);
        float4 n0 = *(const float4*)(nr);
        float4 n1 = *(const float4*)(nr + 4);
        E[i][0] = fmaf(n0.x, L2E, a0.x);
        E[i][1] = fmaf(n0.y, L2E, a0.y);
        E[i][2] = fmaf(n0.z, L2E, a0.z);
        E[i][3] = fmaf(n0.w, L2E, a0.w);
        E[i][4] = fmaf(n1.x, L2E, a1.x);
        E[i][5] = fmaf(n1.y, L2E, a1.y);
        E[i][6] = fmaf(n1.z, L2E, a1.z);
        E[i][7] = fmaf(n1.w, L2E, a1.w);
    }

    // init: row logsumexp2 (max-stabilized); E = 2^(y0 - R1) <= 1
#pragma unroll
    for (int i = 0; i < 4; i++) {
        float mx = E[i][0];
#pragma unroll
        for (int j = 1; j < 8; j++) mx = fmaxf(mx, E[i][j]);
#pragma unroll
        for (int s = 1; s < 16; s <<= 1) mx = fmaxf(mx, __shfl_xor(mx, s));
        float sm = 0.f;
#pragma unroll
        for (int j = 0; j < 8; j++) sm += fexp2(E[i][j] - mx);
#pragma unroll
        for (int s = 1; s < 16; s <<= 1) sm += __shfl_xor(sm, s);
        float R1 = mx + flog2(sm);
#pragma unroll
        for (int j = 0; j < 8; j++) E[i][j] = fexp2(E[i][j] - R1);
    }

    // ---- build F = E^T slice via 2-pass LDS transpose ----
    float F[8][4];
    // pass 1: matrix rows 0..63
    if (tr < 16) {
#pragma unroll
        for (int i = 0; i < 4; i++) {
            *(float4*)&buf[r0 + i][c0]     = make_float4(E[i][0], E[i][1], E[i][2], E[i][3]);
            *(float4*)&buf[r0 + i][c0 + 4] = make_float4(E[i][4], E[i][5], E[i][6], E[i][7]);
        }
    }
    __syncthreads();
    if (tc < 8) {
#pragma unroll
        for (int j = 0; j < 8; j++) {
            float4 v = *(const float4*)&buf[c0 + j][r0];
            F[j][0] = v.x; F[j][1] = v.y; F[j][2] = v.z; F[j][3] = v.w;
        }
    }
    __syncthreads();
    // pass 2: matrix rows 64..127
    if (tr >= 16) {
#pragma unroll
        for (int i = 0; i < 4; i++) {
            *(float4*)&buf[r0 - 64 + i][c0]     = make_float4(E[i][0], E[i][1], E[i][2], E[i][3]);
            *(float4*)&buf[r0 - 64 + i][c0 + 4] = make_float4(E[i][4], E[i][5], E[i][6], E[i][7]);
        }
    }
    __syncthreads();
    if (tc >= 8) {
#pragma unroll
        for (int j = 0; j < 8; j++) {
            float4 v = *(const float4*)&buf[c0 - 64 + j][r0];
            F[j][0] = v.x; F[j][1] = v.y; F[j][2] = v.z; F[j][3] = v.w;
        }
    }

    float uj[8], ti[4];

    for (int k = 0; k < 10; k++) {
        // ---- column pass on F: ti[i] = 1 / sum_r F[.][i]*u ----
        if (k > 0) {
            float4 u0 = *(const float4*)&ubuf[c0];
            float4 u1 = *(const float4*)&ubuf[c0 + 4];
            uj[0] = u0.x; uj[1] = u0.y; uj[2] = u0.z; uj[3] = u0.w;
            uj[4] = u1.x; uj[5] = u1.y; uj[6] = u1.z; uj[7] = u1.w;
        } else {
#pragma unroll
            for (int j = 0; j < 8; j++) uj[j] = 1.f;
        }
#pragma unroll
        for (int i = 0; i < 4; i++) {
            float s = 0.f;
#pragma unroll
            for (int j = 0; j < 8; j++) s = fmaf(F[j][i], uj[j], s);
#pragma unroll
            for (int sf = 1; sf < 16; sf <<= 1) s += __shfl_xor(s, sf);
            ti[i] = frcp(s);
        }
        if (tc == 0)
            *(float4*)&tbuf[r0] = make_float4(ti[0], ti[1], ti[2], ti[3]);
        __syncthreads();

        if (k < 9) {
            // ---- row pass on E: u[r] = 1 / sum_c E[r][.]*t ----
            float tj[8];
            float4 t0 = *(const float4*)&tbuf[c0];
            float4 t1 = *(const float4*)&tbuf[c0 + 4];
            tj[0] = t0.x; tj[1] = t0.y; tj[2] = t0.z; tj[3] = t0.w;
            tj[4] = t1.x; tj[5] = t1.y; tj[6] = t1.z; tj[7] = t1.w;
            float uo[4];
#pragma unroll
            for (int i = 0; i < 4; i++) {
                float s = 0.f;
#pragma unroll
                for (int j = 0; j < 8; j++) s = fmaf(E[i][j], tj[j], s);
#pragma unroll
                for (int sf = 1; sf < 16; sf <<= 1) s += __shfl_xor(s, sf);
                uo[i] = frcp(s);
            }
            if (tc == 0)
                *(float4*)&ubuf[r0] = make_float4(uo[0], uo[1], uo[2], uo[3]);
            __syncthreads();
        } else {
            // ---- final store from F layout: out[m][c][r], coalesced ----
            float* ob = out + (size_t)m * NN * NN;
#pragma unroll
            for (int i = 0; i < 4; i++) {
                float4 v0, v1;
                v0.x = F[0][i] * uj[0] * ti[i];
                v0.y = F[1][i] * uj[1] * ti[i];
                v0.z = F[2][i] * uj[2] * ti[i];
                v0.w = F[3][i] * uj[3] * ti[i];
                v1.x = F[4][i] * uj[4] * ti[i];
                v1.y = F[5][i] * uj[5] * ti[i];
                v1.z = F[6][i] * uj[6] * ti[i];
                v1.w = F[7][i] * uj[7] * ti[i];
                *(float4*)(ob + (size_t)(r0 + i) * NN + c0)     = v0;
                *(float4*)(ob + (size_t)(r0 + i) * NN + c0 + 4) = v1;
            }
        }
    }
}

extern "C" void kernel_launch(void* const* d_in, const int* in_sizes, int n_in,
                              void* d_out, int out_size, void* d_ws, size_t ws_size,
                              hipStream_t stream) {
    const float* x     = (const float*)d_in[0];
    const float* w1    = (const float*)d_in[1];
    const float* b1    = (const float*)d_in[2];
    const float* w2    = (const float*)d_in[3];
    const float* b2    = (const float*)d_in[4];
    const float* noise = (const float*)d_in[5];
    float* out = (float*)d_out;

    char* ws  = (char*)d_ws;
    float*  la  = (float*)ws;                         // 33,554,432 B
    ushort* Bhi = (ushort*)(ws + 33554432);           // 32 KB
    ushort* Blo = (ushort*)(ws + 33554432 + 32768);   // 32 KB
    float*  b2s = (float*)(ws + 33554432 + 65536);    // 512 B

    hipLaunchKernelGGL(prep_kernel, dim3(8), dim3(256), 0, stream,
                       w2, b2, Bhi, Blo, b2s);
    hipLaunchKernelGGL(mlp_mfma_kernel, dim3(1024), dim3(256), 0, stream,
                       x, w1, b1, Bhi, Blo, b2s, la);
    hipLaunchKernelGGL(sinkhorn_kernel, dim3(NMAT), dim3(512), 0, stream,
                       la, noise, out);
}

// Round 5
// 138.160 us; speedup vs baseline: 1.5535x; 1.5535x over previous
//
#include <hip/hip_runtime.h>

#define NN   128
#define NB   512
#define NMAT 2560
#define L2E  1.4426950408889634f

typedef __attribute__((ext_vector_type(4))) float  f32x4;
typedef __attribute__((ext_vector_type(4))) int    i32x4;
typedef __attribute__((ext_vector_type(8))) ushort u16x8;

__device__ __forceinline__ float fexp2(float x){ float r; asm("v_exp_f32 %0, %1" : "=v"(r) : "v"(x)); return r; }
__device__ __forceinline__ float flog2(float x){ float r; asm("v_log_f32 %0, %1" : "=v"(r) : "v"(x)); return r; }
__device__ __forceinline__ float frcp (float x){ float r; asm("v_rcp_f32 %0, %1" : "=v"(r) : "v"(x)); return r; }

__device__ __forceinline__ ushort f2bf(float f){
    unsigned u = __float_as_uint(f);
    unsigned r = (u + 0x7FFFu + ((u >> 16) & 1u)) >> 16;
    return (ushort)r;
}
__device__ __forceinline__ float bf2f(ushort h){ return __uint_as_float(((unsigned)h) << 16); }

#define MFMA16(acc, a, b) \
    asm("v_mfma_f32_16x16x32_bf16 %0, %1, %2, %0" : "+v"(acc) : "v"(a), "v"(b))

// ---------------------------------------------------------------------------
// Prep kernel: permute w2*log2e into MFMA B-fragment order, split bf16 hi/lo.
// ---------------------------------------------------------------------------
__global__ __launch_bounds__(256) void prep_kernel(
    const float* __restrict__ w2, const float* __restrict__ b2,
    ushort* __restrict__ Bhi, ushort* __restrict__ Blo, float* __restrict__ b2s)
{
    int fid = blockIdx.x * 256 + threadIdx.x;    // 0..2047
    int ct = fid >> 8, ks = (fid >> 6) & 3, lane = fid & 63;
    int c  = ct * 16 + (lane & 15);
    int k0 = ks * 32 + ((lane >> 4) << 3);
    u16x8 hi, lo;
#pragma unroll
    for (int j = 0; j < 8; j++) {
        float v = w2[c * NN + k0 + j] * L2E;
        ushort h = f2bf(v);
        hi[j] = h;
        lo[j] = f2bf(v - bf2f(h));
    }
    *(u16x8*)(Bhi + (size_t)fid * 8) = hi;
    *(u16x8*)(Blo + (size_t)fid * 8) = lo;
    if (fid < NN) b2s[fid] = b2[fid] * L2E;
}

// ---------------------------------------------------------------------------
// MLP -> la via MFMA (split bf16: hi@whi + hi@wlo + lo@whi). No LDS/barriers.
// ---------------------------------------------------------------------------
__global__ __launch_bounds__(256) void mlp_mfma_kernel(
    const float* __restrict__ x,  const float* __restrict__ w1,
    const float* __restrict__ b1, const ushort* __restrict__ Bhi,
    const ushort* __restrict__ Blo, const float* __restrict__ b2s,
    float* __restrict__ la)
{
    const int t    = threadIdx.x;
    const int w    = t >> 6;
    const int lane = t & 63;
    const int blk  = blockIdx.x;
    const int b    = blk >> 1;
    const int rh   = blk & 1;

    const int r = rh * 64 + w * 16 + (lane & 15);
    const float xv = x[b * NN + r];

    i32x4 Ahi[4], Alo[4];
#pragma unroll
    for (int ks = 0; ks < 4; ks++) {
        const int l0 = ks * 32 + ((lane >> 4) << 3);
        float4 w1a = *(const float4*)(w1 + l0);
        float4 w1b = *(const float4*)(w1 + l0 + 4);
        float4 b1a = *(const float4*)(b1 + l0);
        float4 b1b = *(const float4*)(b1 + l0 + 4);
        float h[8];
        h[0] = fmaxf(fmaf(xv, w1a.x, b1a.x), 0.f);
        h[1] = fmaxf(fmaf(xv, w1a.y, b1a.y), 0.f);
        h[2] = fmaxf(fmaf(xv, w1a.z, b1a.z), 0.f);
        h[3] = fmaxf(fmaf(xv, w1a.w, b1a.w), 0.f);
        h[4] = fmaxf(fmaf(xv, w1b.x, b1b.x), 0.f);
        h[5] = fmaxf(fmaf(xv, w1b.y, b1b.y), 0.f);
        h[6] = fmaxf(fmaf(xv, w1b.z, b1b.z), 0.f);
        h[7] = fmaxf(fmaf(xv, w1b.w, b1b.w), 0.f);
#pragma unroll
        for (int p = 0; p < 4; p++) {
            ushort h0 = f2bf(h[2 * p]);
            ushort h1 = f2bf(h[2 * p + 1]);
            ushort l0e = f2bf(h[2 * p]     - bf2f(h0));
            ushort l1e = f2bf(h[2 * p + 1] - bf2f(h1));
            ((int*)&Ahi[ks])[p] = ((int)h1 << 16) | (int)h0;
            ((int*)&Alo[ks])[p] = ((int)l1e << 16) | (int)l0e;
        }
    }

    f32x4 acc[8];
#pragma unroll
    for (int ct = 0; ct < 8; ct++) acc[ct] = (f32x4){0.f, 0.f, 0.f, 0.f};

    asm volatile("s_nop 7");

#pragma unroll
    for (int ks = 0; ks < 4; ks++) {
#pragma unroll
        for (int ct = 0; ct < 8; ct++) {
            const size_t off = ((size_t)(ct * 4 + ks) * 64 + lane) * 8;
            i32x4 bh = *(const i32x4*)(Bhi + off);
            i32x4 bl = *(const i32x4*)(Blo + off);
            MFMA16(acc[ct], Ahi[ks], bh);
            MFMA16(acc[ct], Ahi[ks], bl);
            MFMA16(acc[ct], Alo[ks], bh);
        }
    }

    asm volatile("s_nop 7");
    asm volatile("s_nop 7");
    asm volatile("s_nop 3");

    const int row0 = b * NN + rh * 64 + w * 16 + (lane >> 4) * 4;
    const int col  = lane & 15;
#pragma unroll
    for (int ct = 0; ct < 8; ct++) {
        float bb = b2s[ct * 16 + col];
        float* lp = la + (size_t)row0 * NN + ct * 16 + col;
#pragma unroll
        for (int q = 0; q < 4; q++)
            lp[(size_t)q * NN] = acc[ct][q] + bb;
    }
}

// ---------------------------------------------------------------------------
// Kernel 2: Sinkhorn, potential form, base-2 log domain.
// 512 threads, thread tile 4 rows x 8 cols (E = 32 VGPRs, single layout).
// Column reduce is HIERARCHICAL:
//   (1) in-wave: shfl_xor(16,32) collapses the wave's 16-row band,
//   (2) lanes<16 write the 8x128 per-wave partial matrix (2 x b128),
//   (3) threads 0..127 sum 8 sequential conflict-free b32 reads -> tbuf.
// Row reduce: shfl_xor(1,2,4,8) over tc lanes; u never touches LDS.
// ---------------------------------------------------------------------------
__global__ __launch_bounds__(512, 6) void sinkhorn_kernel(
    const float* __restrict__ la, const float* __restrict__ noise,
    float* __restrict__ out)
{
    __shared__ float part[8][132];   // per-wave column partials
    __shared__ float tbuf[128];

    const int m    = blockIdx.x;
    const int b    = m & (NB - 1);
    const int t    = threadIdx.x;
    const int wv   = t >> 6;
    const int lane = t & 63;
    const int tr   = t >> 4, tc = t & 15;
    const int r0   = tr * 4,  c0 = tc * 8;

    const float* lab = la    + (size_t)b * NN * NN;
    const float* nb  = noise + (size_t)m * NN * NN;

    float E[4][8];
#pragma unroll
    for (int i = 0; i < 4; i++) {
        const float* lr = lab + (r0 + i) * NN + c0;
        const float* nr = nb  + (r0 + i) * NN + c0;
        float4 a0 = *(const float4*)(lr);
        float4 a1 = *(const float4*)(lr + 4);
        float4 n0 = *(const float4*)(nr);
        float4 n1 = *(const float4*)(nr + 4);
        E[i][0] = fmaf(n0.x, L2E, a0.x);
        E[i][1] = fmaf(n0.y, L2E, a0.y);
        E[i][2] = fmaf(n0.z, L2E, a0.z);
        E[i][3] = fmaf(n0.w, L2E, a0.w);
        E[i][4] = fmaf(n1.x, L2E, a1.x);
        E[i][5] = fmaf(n1.y, L2E, a1.y);
        E[i][6] = fmaf(n1.z, L2E, a1.z);
        E[i][7] = fmaf(n1.w, L2E, a1.w);
    }

    // init: row logsumexp2 (max-stabilized); E = 2^(y0 - R1) <= 1
#pragma unroll
    for (int i = 0; i < 4; i++) {
        float mx = E[i][0];
#pragma unroll
        for (int j = 1; j < 8; j++) mx = fmaxf(mx, E[i][j]);
#pragma unroll
        for (int s = 1; s < 16; s <<= 1) mx = fmaxf(mx, __shfl_xor(mx, s));
        float sm = 0.f;
#pragma unroll
        for (int j = 0; j < 8; j++) sm += fexp2(E[i][j] - mx);
#pragma unroll
        for (int s = 1; s < 16; s <<= 1) sm += __shfl_xor(sm, s);
        float R1 = mx + flog2(sm);
#pragma unroll
        for (int j = 0; j < 8; j++) E[i][j] = fexp2(E[i][j] - R1);
    }

    float u[4];
#pragma unroll
    for (int i = 0; i < 4; i++) u[i] = 1.f;
    float tj[8];

    for (int k = 0; k < 10; k++) {
        // ---- column pass: t[c] = 1 / sum_r E*u ----
        float loc[8];
#pragma unroll
        for (int j = 0; j < 8; j++) {
            float s = 0.f;
#pragma unroll
            for (int i = 0; i < 4; i++) s = fmaf(E[i][j], u[i], s);
            loc[j] = s;
        }
        // in-wave band reduce: lanes differing in bits 4,5 hold other rows
#pragma unroll
        for (int j = 0; j < 8; j++) {
            loc[j] += __shfl_xor(loc[j], 16);
            loc[j] += __shfl_xor(loc[j], 32);
        }
        if (lane < 16) {
            *(float4*)&part[wv][c0]     = make_float4(loc[0], loc[1], loc[2], loc[3]);
            *(float4*)&part[wv][c0 + 4] = make_float4(loc[4], loc[5], loc[6], loc[7]);
        }
        __syncthreads();
        if (t < NN) {
            float cs = part[0][t];
#pragma unroll
            for (int p = 1; p < 8; p++) cs += part[p][t];
            tbuf[t] = frcp(cs);
        }
        __syncthreads();
        {
            float4 t0 = *(const float4*)&tbuf[c0];
            float4 t1 = *(const float4*)&tbuf[c0 + 4];
            tj[0] = t0.x; tj[1] = t0.y; tj[2] = t0.z; tj[3] = t0.w;
            tj[4] = t1.x; tj[5] = t1.y; tj[6] = t1.z; tj[7] = t1.w;
        }
        // ---- row pass: u[r] = 1 / sum_c E*t (skipped after last col pass) --
        if (k < 9) {
#pragma unroll
            for (int i = 0; i < 4; i++) {
                float s = 0.f;
#pragma unroll
                for (int j = 0; j < 8; j++) s = fmaf(E[i][j], tj[j], s);
#pragma unroll
                for (int sf = 1; sf < 16; sf <<= 1) s += __shfl_xor(s, sf);
                u[i] = frcp(s);
            }
        }
    }

    // output (transposed): out[m][c][r] = E[r][c]*u[r]*t[c]
    float* ob = out + (size_t)m * NN * NN;
#pragma unroll
    for (int j = 0; j < 8; j++) {
        float4 v;
        v.x = E[0][j] * u[0] * tj[j];
        v.y = E[1][j] * u[1] * tj[j];
        v.z = E[2][j] * u[2] * tj[j];
        v.w = E[3][j] * u[3] * tj[j];
        *(float4*)(ob + (size_t)(c0 + j) * NN + r0) = v;
    }
}

extern "C" void kernel_launch(void* const* d_in, const int* in_sizes, int n_in,
                              void* d_out, int out_size, void* d_ws, size_t ws_size,
                              hipStream_t stream) {
    const float* x     = (const float*)d_in[0];
    const float* w1    = (const float*)d_in[1];
    const float* b1    = (const float*)d_in[2];
    const float* w2    = (const float*)d_in[3];
    const float* b2    = (const float*)d_in[4];
    const float* noise = (const float*)d_in[5];
    float* out = (float*)d_out;

    char* ws  = (char*)d_ws;
    float*  la  = (float*)ws;                         // 33,554,432 B
    ushort* Bhi = (ushort*)(ws + 33554432);           // 32 KB
    ushort* Blo = (ushort*)(ws + 33554432 + 32768);   // 32 KB
    float*  b2s = (float*)(ws + 33554432 + 65536);    // 512 B

    hipLaunchKernelGGL(prep_kernel, dim3(8), dim3(256), 0, stream,
                       w2, b2, Bhi, Blo, b2s);
    hipLaunchKernelGGL(mlp_mfma_kernel, dim3(1024), dim3(256), 0, stream,
                       x, w1, b1, Bhi, Blo, b2s, la);
    hipLaunchKernelGGL(sinkhorn_kernel, dim3(NMAT), dim3(512), 0, stream,
                       la, noise, out);
}